// Round 6
// baseline (1386.593 us; speedup 1.0000x reference)
//
#include <hip/hip_runtime.h>

typedef __attribute__((ext_vector_type(8))) short short8;
typedef __attribute__((ext_vector_type(4))) float f32x4;

__device__ __forceinline__ ushort f2bf(float f){
    union { float f; unsigned u; } v; v.f = f;
    unsigned r = (v.u + 0x7fffu + ((v.u >> 16) & 1u)) >> 16;
    return (ushort)r;
}
__device__ __forceinline__ float bf2f(ushort u){
    union { unsigned u; float f; } v; v.u = ((unsigned)u) << 16;
    return v.f;
}

// ---------------- Layer 1: Cin=1 -> 40 real (stored 64, pad zero), direct fp32 ----------
__global__ __launch_bounds__(256) void conv_l1(
    const float* __restrict__ x, const float* __restrict__ w,
    const float* __restrict__ bias, ushort* __restrict__ out)
{
    __shared__ float xs[2916];     // [3][3][18][18] padded neighborhood
    __shared__ float wsh[3240];    // [40][81]
    const int tid = threadIdx.x;
    const int bx = blockIdx.x;
    const int d2 = bx & 15, d1 = (bx >> 4) & 15, b = bx >> 8;
    const float* xb = x + (size_t)b * 65536;

    for (int i = tid; i < 2916; i += 256){
        int i4 = i % 18; int r1 = i / 18; int i3 = r1 % 18;
        int r2 = r1 / 18; int a2 = r2 % 3; int a1 = r2 / 3;
        int e1 = d1 + a1 - 1, e2 = d2 + a2 - 1, e3 = i3 - 1, e4 = i4 - 1;
        float v = 0.f;
        if ((unsigned)e1 < 16u && (unsigned)e2 < 16u && (unsigned)e3 < 16u && (unsigned)e4 < 16u)
            v = xb[((e1 * 16 + e2) * 16 + e3) * 16 + e4];
        xs[i] = v;
    }
    for (int i = tid; i < 3240; i += 256) wsh[i] = w[i];
    __syncthreads();

    const int d3 = tid >> 4, d4 = tid & 15;
    float acc[40];
    #pragma unroll
    for (int c = 0; c < 40; ++c) acc[c] = 0.f;

    for (int t1 = 0; t1 < 3; ++t1)
    for (int t2 = 0; t2 < 3; ++t2)
    for (int t3 = 0; t3 < 3; ++t3)
    #pragma unroll
    for (int t4 = 0; t4 < 3; ++t4){
        float xv = xs[((t1 * 3 + t2) * 18 + d3 + t3) * 18 + d4 + t4];
        int tap = ((t1 * 3 + t2) * 3 + t3) * 3 + t4;
        #pragma unroll
        for (int c = 0; c < 40; ++c) acc[c] += wsh[c * 81 + tap] * xv;
    }

    ushort* ob = out + ((size_t)bx * 256 + tid) * 64;
    #pragma unroll
    for (int c = 0; c < 40; ++c){
        float v = acc[c] + bias[c]; v = v > 0.f ? v : 0.f;
        ob[c] = f2bf(v);
    }
    #pragma unroll
    for (int c = 40; c < 64; ++c) ob[c] = 0;
}

// ---------------- Layer 6: 40 real (stored 64) -> Cout=1, direct fp32 -------------------
__global__ __launch_bounds__(256) void conv_l6(
    const ushort* __restrict__ in, const float* __restrict__ w,
    const float* __restrict__ bias, float* __restrict__ out)
{
    __shared__ float wsh[3240];    // [ci=40][81]
    const int tid = threadIdx.x;
    const int bx = blockIdx.x;
    const int d2 = bx & 15, d1 = (bx >> 4) & 15, b = bx >> 8;
    for (int i = tid; i < 3240; i += 256) wsh[i] = w[i];
    __syncthreads();

    const int d3 = tid >> 4, d4 = tid & 15;
    const ushort* inb = in + (size_t)b * 65536 * 64;
    float acc = 0.f;
    for (int t1 = 0; t1 < 3; ++t1){
        int e1 = d1 + t1 - 1; if ((unsigned)e1 >= 16u) continue;
        for (int t2 = 0; t2 < 3; ++t2){
            int e2 = d2 + t2 - 1; if ((unsigned)e2 >= 16u) continue;
            for (int t3 = 0; t3 < 3; ++t3){
                int e3 = d3 + t3 - 1; if ((unsigned)e3 >= 16u) continue;
                for (int t4 = 0; t4 < 3; ++t4){
                    int e4 = d4 + t4 - 1; if ((unsigned)e4 >= 16u) continue;
                    const ushort* p = inb + (size_t)(((e1 * 16 + e2) * 16 + e3) * 16 + e4) * 64;
                    int tap = ((t1 * 3 + t2) * 3 + t3) * 3 + t4;
                    #pragma unroll
                    for (int c8 = 0; c8 < 5; ++c8){
                        short8 v = *(const short8*)(p + c8 * 8);
                        #pragma unroll
                        for (int j = 0; j < 8; ++j)
                            acc += bf2f((ushort)v[j]) * wsh[(c8 * 8 + j) * 81 + tap];
                    }
                }
            }
        }
    }
    float v = acc + bias[0]; v = v > 0.f ? v : 0.f;
    out[(size_t)bx * 256 + tid] = v;
}

// ---------------- Weight repack: [co][ci][81] fp32 -> [81][ci/8][co][8] bf16 ------------
__global__ void repack_w(const float* __restrict__ w, ushort* __restrict__ wp,
                         int cin, int cout, int cin_s, int cout_c)
{
    const int total = 81 * cin_s * cout_c;
    for (int i = blockIdx.x * blockDim.x + threadIdx.x; i < total; i += gridDim.x * blockDim.x){
        int j = i & 7;
        int rest = i >> 3;
        int co = rest % cout_c;
        int rest2 = rest / cout_c;
        int ci_hi = rest2 % (cin_s >> 3);
        int t = rest2 / (cin_s >> 3);
        int ci = ci_hi * 8 + j;
        float v = (ci < cin && co < cout) ? w[((size_t)co * cin + ci) * 81 + t] : 0.f;
        wp[i] = f2bf(v);
    }
}

// ---------------- MFMA implicit-GEMM conv layer -----------------------------------------
// in : [b][d1][d2][d3][d4][CIN_S]  bf16
// wp : [81][ci/8][COUT_C][8]       bf16 (B-fragment native)
// out: [b][d1][d2][d3][d4][COUT_C] bf16
// K-chunked: chunk = (t1,t2 group, kh 32-ch slice). A [256 pos][32 ch] XOR-swizzled,
// single LDS buffer + register prefetch (2 barriers per chunk). B [32 ch][COUT_C]
// XOR-swizzled, double-buffered, reg prefetch distance 1 tap. Conflict-free both.
// WN=1: 256 thr, 4 waves (wave = 4 d3-rows x full N). WN=2: 512 thr, 8 waves (2 N-halves).
template<int CIN_S, int COUT_C, int WN, int MINW>
__global__ __launch_bounds__(256 * WN, MINW) void conv_mfma(
    const ushort* __restrict__ in, const ushort* __restrict__ wp,
    const float* __restrict__ bias, int cout_real, ushort* __restrict__ out)
{
    constexpr int NTHR = 256 * WN;
    constexpr int KC   = CIN_S / 32;          // 32-ch chunks per tap
    constexpr int NT   = COUT_C / (16 * WN);  // N tiles per wave
    constexpr int NCH  = 9 * KC;              // (group, kh) chunks
    constexpr int NSG  = NCH * 9;             // total sub-steps
    constexpr int A8   = 1024;                // short8 per A chunk (256 pos * 4)
    constexpr int NLA  = A8 / NTHR;
    constexpr int B8   = 4 * COUT_C;          // short8 per B chunk
    constexpr int NLB  = (B8 + NTHR - 1) / NTHR;

    __shared__ __attribute__((aligned(16))) ushort As[8192];        // 16 KB
    __shared__ __attribute__((aligned(16))) ushort Bs[2][B8 * 8];

    const int tid  = threadIdx.x;
    const int lane = tid & 63;
    const int w    = tid >> 6;
    const int wm   = (WN == 2) ? (w >> 1) : w;   // d3 group 0..3
    const int wn   = (WN == 2) ? (w & 1) : 0;    // N half
    const int r    = lane & 15;                  // d4 / B-col / D-col
    const int g    = lane >> 4;                  // k-group / D row-group

    // XCD-aware chunked swizzle (grid=512, 8 XCDs, 64 blocks/XCD-chunk)
    const int p0 = blockIdx.x;
    const int bx = (p0 & 7) * 64 + (p0 >> 3);
    const int d2 = bx & 15, d1 = (bx >> 4) & 15, b = bx >> 8;

    const ushort* inb = in + (size_t)b * 65536 * CIN_S;
    const int co0 = wn * NT * 16;

    f32x4 acc[4][NT];
    #pragma unroll
    for (int f = 0; f < 4; ++f)
        #pragma unroll
        for (int n = 0; n < NT; ++n)
            acc[f][n] = (f32x4){0.f, 0.f, 0.f, 0.f};

    short8 areg[NLA];
    short8 breg[NLB];

    auto loadAreg = [&](int c){
        const int gg = c / KC, kh = c - gg * KC;
        const int t1 = gg / 3, t2 = gg - t1 * 3;
        const int e1 = d1 + t1 - 1, e2 = d2 + t2 - 1;
        if ((unsigned)e1 >= 16u || (unsigned)e2 >= 16u) return;  // chunk never read
        const ushort* src = inb + ((size_t)(e1 * 16 + e2) * 256) * CIN_S + kh * 32;
        #pragma unroll
        for (int k = 0; k < NLA; ++k){
            const int i = tid + k * NTHR;
            const int pos = i >> 2, gc = i & 3;
            areg[k] = *(const short8*)(src + (size_t)pos * CIN_S + gc * 8);
        }
    };
    auto writeA = [&](){
        #pragma unroll
        for (int k = 0; k < NLA; ++k){
            const int i = tid + k * NTHR;
            const int pos = i >> 2, gc = i & 3;
            const int gs = gc ^ ((pos >> 1) & 3);
            *(short8*)(As + pos * 32 + gs * 8) = areg[k];
        }
    };
    auto loadBreg = [&](int sg){
        const int cn = sg / 9, ttn = sg - cn * 9;
        const int tapn = (cn / KC) * 9 + ttn, khn = cn % KC;
        const short8* src = (const short8*)wp + ((size_t)tapn * (CIN_S / 8) + khn * 4) * COUT_C;
        #pragma unroll
        for (int k = 0; k < NLB; ++k){
            const int i = tid + k * NTHR;
            if (i < B8) breg[k] = src[i];
        }
    };
    auto writeB = [&](int s){
        #pragma unroll
        for (int k = 0; k < NLB; ++k){
            const int i = tid + k * NTHR;
            if (i < B8){
                const int ci8 = i / COUT_C;                  // 0..3
                *(short8*)(Bs[s] + ((i * 8) ^ (ci8 << 3))) = breg[k];
            }
        }
    };

    // prologue: chunk 0 A + step 0 B staged
    loadAreg(0);
    loadBreg(0);
    writeA();
    writeB(0);

    for (int sg = 0; sg < NSG; ++sg){
        const int cur = sg & 1;
        const int chunk = sg / 9, tt = sg - chunk * 9;
        const int gg = chunk / KC;
        const int t1 = gg / 3, t2 = gg - t1 * 3;
        const bool gv = ((unsigned)(d1 + t1 - 1) < 16u) && ((unsigned)(d2 + t2 - 1) < 16u);

        if (tt == 0){
            if (sg > 0){
                __syncthreads();      // all reads of previous A chunk done; B[cur] visible
                writeA();
            }
            __syncthreads();          // A visible (and staged B visible)
            if (chunk + 1 < NCH) loadAreg(chunk + 1);   // 9-tap latency budget
        } else {
            __syncthreads();          // B[cur] visible
        }

        if (sg + 1 < NSG) loadBreg(sg + 1);   // global -> regs, drains at writeB below

        if (gv){
            const int t3 = tt / 3, t4 = tt - t3 * 3;
            const int e4 = r + t4 - 1;
            const bool v4 = (unsigned)e4 < 16u;
            const int gsw = (g ^ ((e4 >> 1) & 3)) << 3;   // A swizzle, e3-independent

            short8 bfr[NT];
            #pragma unroll
            for (int n = 0; n < NT; ++n)
                bfr[n] = *(const short8*)(Bs[cur] + (((g * COUT_C + co0 + n * 16 + r) * 8) ^ (g << 3)));

            __builtin_amdgcn_s_setprio(1);
            #pragma unroll
            for (int f = 0; f < 4; ++f){
                const int e3 = wm * 4 + f + t3 - 1;
                if ((unsigned)e3 < 16u){
                    short8 af = {0, 0, 0, 0, 0, 0, 0, 0};
                    if (v4)
                        af = *(const short8*)(As + (e3 * 16 + e4) * 32 + gsw);
                    #pragma unroll
                    for (int n = 0; n < NT; ++n)
                        acc[f][n] = __builtin_amdgcn_mfma_f32_16x16x32_bf16(af, bfr[n], acc[f][n], 0, 0, 0);
                }
            }
            __builtin_amdgcn_s_setprio(0);
        }

        if (sg + 1 < NSG) writeB(cur ^ 1);
    }

    // epilogue: bias + ReLU + bf16 store
    float bv[NT];
    #pragma unroll
    for (int n = 0; n < NT; ++n){
        int co = co0 + n * 16 + r;
        bv[n] = (co < cout_real) ? bias[co] : 0.f;
    }
    ushort* ob = out + (size_t)bx * 256 * COUT_C;
    #pragma unroll
    for (int f = 0; f < 4; ++f){
        const int d3 = wm * 4 + f;
        #pragma unroll
        for (int n = 0; n < NT; ++n){
            const int co = co0 + n * 16 + r;
            #pragma unroll
            for (int j = 0; j < 4; ++j){
                const int d4 = g * 4 + j;
                float v = acc[f][n][j] + bv[n];
                v = v > 0.f ? v : 0.f;
                ob[(size_t)(d3 * 16 + d4) * COUT_C + co] = f2bf(v);
            }
        }
    }
}

extern "C" void kernel_launch(void* const* d_in, const int* in_sizes, int n_in,
                              void* d_out, int out_size, void* d_ws, size_t ws_size,
                              hipStream_t stream) {
    const float* x  = (const float*)d_in[0];
    const float* w1 = (const float*)d_in[1];  const float* b1 = (const float*)d_in[2];
    const float* w2 = (const float*)d_in[3];  const float* b2 = (const float*)d_in[4];
    const float* w3 = (const float*)d_in[5];  const float* b3 = (const float*)d_in[6];
    const float* w4 = (const float*)d_in[7];  const float* b4 = (const float*)d_in[8];
    const float* w5 = (const float*)d_in[9];  const float* b5 = (const float*)d_in[10];
    const float* w6 = (const float*)d_in[11]; const float* b6 = (const float*)d_in[12];

    // workspace layout (bf16 ushorts):
    ushort* bufA = (ushort*)d_ws;                       // [131072][160] : 41.9 MB
    ushort* bufB = bufA + (size_t)131072 * 160;         // [131072][96]  : 25.2 MB
    ushort* wp2  = bufB + (size_t)131072 * 96;          // 81*64*96
    ushort* wp3  = wp2 + (size_t)81 * 64 * 96;          // 81*96*160
    ushort* wp4  = wp3 + (size_t)81 * 96 * 160;         // 81*160*96
    ushort* wp5  = wp4 + (size_t)81 * 160 * 96;         // 81*96*64

    repack_w<<<512, 256, 0, stream>>>(w2, wp2, 40, 80, 64, 96);
    repack_w<<<512, 256, 0, stream>>>(w3, wp3, 80, 160, 96, 160);
    repack_w<<<512, 256, 0, stream>>>(w4, wp4, 160, 80, 160, 96);
    repack_w<<<512, 256, 0, stream>>>(w5, wp5, 80, 40, 96, 64);

    conv_l1<<<512, 256, 0, stream>>>(x, w1, b1, bufA);
    conv_mfma< 64,  96, 1, 2><<<512, 256, 0, stream>>>(bufA, wp2, b2, 80, bufB);
    conv_mfma< 96, 160, 2, 2><<<512, 512, 0, stream>>>(bufB, wp3, b3, 160, bufA);
    conv_mfma<160,  96, 1, 2><<<512, 256, 0, stream>>>(bufA, wp4, b4, 80, bufB);
    conv_mfma< 96,  64, 1, 2><<<512, 256, 0, stream>>>(bufB, wp5, b5, 40, bufA);
    conv_l6<<<512, 256, 0, stream>>>(bufA, w6, b6, (float*)d_out);
}

// Round 7
// 1077.752 us; speedup vs baseline: 1.2866x; 1.2866x over previous
//
#include <hip/hip_runtime.h>

typedef __attribute__((ext_vector_type(8))) short short8;
typedef __attribute__((ext_vector_type(16))) float f32x16;

__device__ __forceinline__ ushort f2bf(float f){
    union { float f; unsigned u; } v; v.f = f;
    unsigned r = (v.u + 0x7fffu + ((v.u >> 16) & 1u)) >> 16;
    return (ushort)r;
}
__device__ __forceinline__ float bf2f(ushort u){
    union { unsigned u; float f; } v; v.u = ((unsigned)u) << 16;
    return v.f;
}

// ---------------- Layer 1: Cin=1 -> 40 real (stored 64, pad zero), direct fp32 ----------
__global__ __launch_bounds__(256) void conv_l1(
    const float* __restrict__ x, const float* __restrict__ w,
    const float* __restrict__ bias, ushort* __restrict__ out)
{
    __shared__ float xs[2916];     // [3][3][18][18] padded neighborhood
    __shared__ float wsh[3240];    // [40][81]
    const int tid = threadIdx.x;
    const int bx = blockIdx.x;
    const int d2 = bx & 15, d1 = (bx >> 4) & 15, b = bx >> 8;
    const float* xb = x + (size_t)b * 65536;

    for (int i = tid; i < 2916; i += 256){
        int i4 = i % 18; int r1 = i / 18; int i3 = r1 % 18;
        int r2 = r1 / 18; int a2 = r2 % 3; int a1 = r2 / 3;
        int e1 = d1 + a1 - 1, e2 = d2 + a2 - 1, e3 = i3 - 1, e4 = i4 - 1;
        float v = 0.f;
        if ((unsigned)e1 < 16u && (unsigned)e2 < 16u && (unsigned)e3 < 16u && (unsigned)e4 < 16u)
            v = xb[((e1 * 16 + e2) * 16 + e3) * 16 + e4];
        xs[i] = v;
    }
    for (int i = tid; i < 3240; i += 256) wsh[i] = w[i];
    __syncthreads();

    const int d3 = tid >> 4, d4 = tid & 15;
    float acc[40];
    #pragma unroll
    for (int c = 0; c < 40; ++c) acc[c] = 0.f;

    for (int t1 = 0; t1 < 3; ++t1)
    for (int t2 = 0; t2 < 3; ++t2)
    for (int t3 = 0; t3 < 3; ++t3)
    #pragma unroll
    for (int t4 = 0; t4 < 3; ++t4){
        float xv = xs[((t1 * 3 + t2) * 18 + d3 + t3) * 18 + d4 + t4];
        int tap = ((t1 * 3 + t2) * 3 + t3) * 3 + t4;
        #pragma unroll
        for (int c = 0; c < 40; ++c) acc[c] += wsh[c * 81 + tap] * xv;
    }

    ushort* ob = out + ((size_t)bx * 256 + tid) * 64;
    #pragma unroll
    for (int c = 0; c < 40; ++c){
        float v = acc[c] + bias[c]; v = v > 0.f ? v : 0.f;
        ob[c] = f2bf(v);
    }
    #pragma unroll
    for (int c = 40; c < 64; ++c) ob[c] = 0;
}

// ---------------- Layer 6: 40 real (stored 64) -> Cout=1, direct fp32 -------------------
__global__ __launch_bounds__(256) void conv_l6(
    const ushort* __restrict__ in, const float* __restrict__ w,
    const float* __restrict__ bias, float* __restrict__ out)
{
    __shared__ float wsh[3240];    // [ci=40][81]
    const int tid = threadIdx.x;
    const int bx = blockIdx.x;
    const int d2 = bx & 15, d1 = (bx >> 4) & 15, b = bx >> 8;
    for (int i = tid; i < 3240; i += 256) wsh[i] = w[i];
    __syncthreads();

    const int d3 = tid >> 4, d4 = tid & 15;
    const ushort* inb = in + (size_t)b * 65536 * 64;
    float acc = 0.f;
    for (int t1 = 0; t1 < 3; ++t1){
        int e1 = d1 + t1 - 1; if ((unsigned)e1 >= 16u) continue;
        for (int t2 = 0; t2 < 3; ++t2){
            int e2 = d2 + t2 - 1; if ((unsigned)e2 >= 16u) continue;
            for (int t3 = 0; t3 < 3; ++t3){
                int e3 = d3 + t3 - 1; if ((unsigned)e3 >= 16u) continue;
                for (int t4 = 0; t4 < 3; ++t4){
                    int e4 = d4 + t4 - 1; if ((unsigned)e4 >= 16u) continue;
                    const ushort* p = inb + (size_t)(((e1 * 16 + e2) * 16 + e3) * 16 + e4) * 64;
                    int tap = ((t1 * 3 + t2) * 3 + t3) * 3 + t4;
                    #pragma unroll
                    for (int c8 = 0; c8 < 5; ++c8){
                        short8 v = *(const short8*)(p + c8 * 8);
                        #pragma unroll
                        for (int j = 0; j < 8; ++j)
                            acc += bf2f((ushort)v[j]) * wsh[(c8 * 8 + j) * 81 + tap];
                    }
                }
            }
        }
    }
    float v = acc + bias[0]; v = v > 0.f ? v : 0.f;
    out[(size_t)bx * 256 + tid] = v;
}

// ---------------- Weight repack: [co][ci][81] fp32 -> [81][ci/8][co][8] bf16 ------------
__global__ void repack_w(const float* __restrict__ w, ushort* __restrict__ wp,
                         int cin, int cout, int cin_s, int cout_c)
{
    const int total = 81 * cin_s * cout_c;
    for (int i = blockIdx.x * blockDim.x + threadIdx.x; i < total; i += gridDim.x * blockDim.x){
        int j = i & 7;
        int rest = i >> 3;
        int co = rest % cout_c;
        int rest2 = rest / cout_c;
        int ci_hi = rest2 % (cin_s >> 3);
        int t = rest2 / (cin_s >> 3);
        int ci = ci_hi * 8 + j;
        float v = (ci < cin && co < cout) ? w[((size_t)co * cin + ci) * 81 + t] : 0.f;
        wp[i] = f2bf(v);
    }
}

// ---------------- 32x32x16 MFMA implicit-GEMM conv layer --------------------------------
// in : [b][d1][d2][d3][d4][CIN_S]  bf16
// wp : [81][ci/8][COUT_C][8]       bf16 (B-fragment native)
// out: [b][d1][d2][d3][d4][OST]    bf16 (cols >= OST dropped; zeros via zero weights)
// Wave tile M=64 x N=COUT_C/WN via 32x32x16 frags (m2 x NT). Steps = (valid group, kh, t3),
// each staging B for the 3 t4-taps (36*NT/3 MFMA per barrier). A chunk [256 pos][32ch]
// double-buffered, reg-prefetched 1 chunk ahead. B reg-prefetched 2 steps ahead.
template<int CIN_S, int COUT_C, int OST, int WN>
__global__ __launch_bounds__(256 * WN, 2) void conv32(
    const ushort* __restrict__ in, const ushort* __restrict__ wp,
    const float* __restrict__ bias, int cout_real, ushort* __restrict__ out)
{
    constexpr int NTHR = 256 * WN;
    constexpr int KC   = CIN_S / 32;           // A chunks per plane
    constexpr int NT   = COUT_C / (32 * WN);   // n-frags per wave
    constexpr int APAD = 40;                   // A row stride in shorts (odd 16B-slot count)
    constexpr int A8   = 1024;                 // 16B units per A chunk (256 pos x 4)
    constexpr int NLA  = A8 / NTHR;
    constexpr int B8   = 12 * COUT_C;          // 16B units per 3-tap B chunk
    constexpr int NLB  = (B8 + NTHR - 1) / NTHR;

    __shared__ __attribute__((aligned(16))) ushort As[2][256 * APAD];
    __shared__ __attribute__((aligned(16))) ushort Bs[2][B8 * 8];

    const int tid  = threadIdx.x;
    const int lane = tid & 63;
    const int wv   = tid >> 6;
    const int wm   = (WN == 2) ? (wv >> 1) : wv;   // M quarter (64 rows each)
    const int wn   = (WN == 2) ? (wv & 1) : 0;
    const int r32  = lane & 31;
    const int ko   = lane >> 5;                    // k-octet

    // XCD-aware chunked swizzle (grid=512, 8 XCDs, 64 blocks/XCD-chunk)
    const int p0 = blockIdx.x;
    const int bx = (p0 & 7) * 64 + (p0 >> 3);
    const int d2 = bx & 15, d1 = (bx >> 4) & 15, b = bx >> 8;

    const ushort* inb = in + (size_t)b * 65536 * CIN_S;
    const int co0 = wn * (COUT_C / WN);

    // valid (t1,t2) groups packed 4 bits each (no runtime-indexed array -> stays in regs)
    unsigned long long gpack = 0ull; int ng = 0;
    #pragma unroll
    for (int gg = 0; gg < 9; ++gg){
        const int t1 = gg / 3, t2 = gg - (gg / 3) * 3;
        if ((unsigned)(d1 + t1 - 1) < 16u && (unsigned)(d2 + t2 - 1) < 16u){
            gpack |= ((unsigned long long)gg) << (ng * 4);
            ++ng;
        }
    }
    const int nchunk = ng * KC;
    const int nstep  = nchunk * 3;

    f32x16 acc[2][NT];
    #pragma unroll
    for (int mi = 0; mi < 2; ++mi)
        #pragma unroll
        for (int n = 0; n < NT; ++n)
            #pragma unroll
            for (int j = 0; j < 16; ++j)
                acc[mi][n][j] = 0.f;

    short8 areg[NLA];
    short8 brg0[NLB], brg1[NLB];

    auto loadAreg = [&](int c){
        const int gi = c / KC, kh = c - gi * KC;
        const int gg = (int)((gpack >> (gi * 4)) & 15ull);
        const int t1 = gg / 3, t2 = gg - t1 * 3;
        const ushort* src = inb + ((size_t)((d1 + t1 - 1) * 16 + (d2 + t2 - 1)) * 256) * CIN_S + kh * 32;
        #pragma unroll
        for (int k = 0; k < NLA; ++k){
            const int i = tid + k * NTHR;
            areg[k] = *(const short8*)(src + (size_t)(i >> 2) * CIN_S + (i & 3) * 8);
        }
    };
    auto writeA = [&](ushort* dst){
        #pragma unroll
        for (int k = 0; k < NLA; ++k){
            const int i = tid + k * NTHR;
            *(short8*)(dst + (i >> 2) * APAD + (i & 3) * 8) = areg[k];
        }
    };
    auto loadBreg = [&](int s, short8 (&brg)[NLB]){
        const int c = s / 3, t3 = s - c * 3;
        const int gi = c / KC, kh = c - gi * KC;
        const int gg = (int)((gpack >> (gi * 4)) & 15ull);
        const int tap0 = gg * 9 + t3 * 3;          // t4 = 0
        const short8* src = (const short8*)wp + ((size_t)tap0 * (CIN_S / 8) + kh * 4) * COUT_C;
        #pragma unroll
        for (int k = 0; k < NLB; ++k){
            const int i = tid + k * NTHR;
            if (i < B8){
                const int t4 = i / (4 * COUT_C), rest = i - t4 * (4 * COUT_C);
                brg[k] = src[(size_t)t4 * (CIN_S / 8) * COUT_C + rest];
            }
        }
    };
    auto writeB = [&](ushort* dst, short8 (&brg)[NLB]){
        #pragma unroll
        for (int k = 0; k < NLB; ++k){
            const int i = tid + k * NTHR;
            if (i < B8) *(short8*)(dst + i * 8) = brg[k];
        }
    };

    // prologue
    loadAreg(0);
    loadBreg(0, brg0);
    writeA(As[0]);
    writeB(Bs[0], brg0);
    if (nchunk > 1) loadAreg(1);
    if (nstep > 1) loadBreg(1, brg1);
    __syncthreads();

    int c = 0, t3 = 0;
    for (int s = 0; s < nstep; ++s){
        // ds-write next B chunk (regs loaded 2 steps ago -> no vmcnt stall)
        if (s + 1 < nstep){
            if ((s + 1) & 1) writeB(Bs[1], brg1); else writeB(Bs[0], brg0);
        }
        // ds-write next A chunk (regs loaded >= 2 steps ago)
        if (t3 == 0 && c + 1 < nchunk) writeA(As[(c + 1) & 1]);
        if (t3 == 1 && c + 2 < nchunk) loadAreg(c + 2);
        // issue global loads for B two steps ahead
        if (s + 2 < nstep){
            if (s & 1) loadBreg(s + 2, brg1); else loadBreg(s + 2, brg0);
        }

        // compute: 3 t4-taps x 2 kf x (m2 x NT) MFMA
        const ushort* Ab = As[c & 1];
        const ushort* Bb = Bs[s & 1];
        __builtin_amdgcn_s_setprio(1);
        #pragma unroll
        for (int t4 = 0; t4 < 3; ++t4){
            const int e4 = (r32 & 15) + t4 - 1;
            const bool v4 = (unsigned)e4 < 16u;
            #pragma unroll
            for (int kf = 0; kf < 2; ++kf){
                short8 bfr[NT];
                #pragma unroll
                for (int n = 0; n < NT; ++n)
                    bfr[n] = *(const short8*)(Bb + ((t4 * 4 + kf * 2 + ko) * COUT_C + co0 + n * 32 + r32) * 8);
                #pragma unroll
                for (int mi = 0; mi < 2; ++mi){
                    const int d3 = 4 * wm + 2 * mi + (r32 >> 4);
                    const int e3 = d3 + t3 - 1;
                    short8 af = {0, 0, 0, 0, 0, 0, 0, 0};
                    if (v4 && (unsigned)e3 < 16u)
                        af = *(const short8*)(Ab + (e3 * 16 + e4) * APAD + kf * 16 + ko * 8);
                    #pragma unroll
                    for (int n = 0; n < NT; ++n)
                        acc[mi][n] = __builtin_amdgcn_mfma_f32_32x32x16_bf16(af, bfr[n], acc[mi][n], 0, 0, 0);
                }
            }
        }
        __builtin_amdgcn_s_setprio(0);

        __syncthreads();
        ++t3; if (t3 == 3){ t3 = 0; ++c; }
    }

    // epilogue: bias + ReLU + bf16 store.  D frag: col = lane&31, row = (reg&3)+8*(reg>>2)+4*ko
    ushort* ob = out + (size_t)bx * 256 * OST;
    #pragma unroll
    for (int mi = 0; mi < 2; ++mi){
        #pragma unroll
        for (int n = 0; n < NT; ++n){
            const int co = co0 + n * 32 + r32;
            if (co < OST){
                const float bv = (co < cout_real) ? bias[co] : 0.f;
                #pragma unroll
                for (int reg = 0; reg < 16; ++reg){
                    const int row = 64 * wm + 32 * mi + (reg & 3) + 8 * (reg >> 2) + 4 * ko;
                    float v = acc[mi][n][reg] + bv;
                    v = v > 0.f ? v : 0.f;
                    ob[(size_t)row * OST + co] = f2bf(v);
                }
            }
        }
    }
}

extern "C" void kernel_launch(void* const* d_in, const int* in_sizes, int n_in,
                              void* d_out, int out_size, void* d_ws, size_t ws_size,
                              hipStream_t stream) {
    const float* x  = (const float*)d_in[0];
    const float* w1 = (const float*)d_in[1];  const float* b1 = (const float*)d_in[2];
    const float* w2 = (const float*)d_in[3];  const float* b2 = (const float*)d_in[4];
    const float* w3 = (const float*)d_in[5];  const float* b3 = (const float*)d_in[6];
    const float* w4 = (const float*)d_in[7];  const float* b4 = (const float*)d_in[8];
    const float* w5 = (const float*)d_in[9];  const float* b5 = (const float*)d_in[10];
    const float* w6 = (const float*)d_in[11]; const float* b6 = (const float*)d_in[12];

    // workspace layout (bf16 ushorts):
    ushort* bufA = (ushort*)d_ws;                       // [131072][160] : 41.9 MB
    ushort* bufB = bufA + (size_t)131072 * 160;         // [131072][96]  : 25.2 MB
    ushort* wp2  = bufB + (size_t)131072 * 96;          // 81*64*96
    ushort* wp3  = wp2 + (size_t)81 * 64 * 96;          // 81*96*192 (cout padded to 192)
    ushort* wp4  = wp3 + (size_t)81 * 96 * 192;         // 81*160*96
    ushort* wp5  = wp4 + (size_t)81 * 160 * 96;         // 81*96*64

    repack_w<<<512, 256, 0, stream>>>(w2, wp2, 40, 80, 64, 96);
    repack_w<<<512, 256, 0, stream>>>(w3, wp3, 80, 160, 96, 192);
    repack_w<<<512, 256, 0, stream>>>(w4, wp4, 160, 80, 160, 96);
    repack_w<<<512, 256, 0, stream>>>(w5, wp5, 80, 40, 96, 64);

    conv_l1<<<512, 256, 0, stream>>>(x, w1, b1, bufA);
    conv32< 64,  96,  96, 1><<<512, 256, 0, stream>>>(bufA, wp2, b2, 80, bufB);
    conv32< 96, 192, 160, 2><<<512, 512, 0, stream>>>(bufB, wp3, b3, 160, bufA);
    conv32<160,  96,  96, 1><<<512, 256, 0, stream>>>(bufA, wp4, b4, 80, bufB);
    conv32< 96,  64,  64, 1><<<512, 256, 0, stream>>>(bufB, wp5, b5, 40, bufA);
    conv_l6<<<512, 256, 0, stream>>>(bufA, w6, b6, (float*)d_out);
}

// Round 8
// 950.882 us; speedup vs baseline: 1.4582x; 1.1334x over previous
//
#include <hip/hip_runtime.h>

typedef __attribute__((ext_vector_type(8))) short short8;
typedef __attribute__((ext_vector_type(4))) float f32x4;

__device__ __forceinline__ ushort f2bf(float f){
    union { float f; unsigned u; } v; v.f = f;
    unsigned r = (v.u + 0x7fffu + ((v.u >> 16) & 1u)) >> 16;
    return (ushort)r;
}
__device__ __forceinline__ float bf2f(ushort u){
    union { unsigned u; float f; } v; v.u = ((unsigned)u) << 16;
    return v.f;
}

// ---------------- Layer 1: Cin=1 -> 40 real (stored 64, pad zero), direct fp32 ----------
__global__ __launch_bounds__(256) void conv_l1(
    const float* __restrict__ x, const float* __restrict__ w,
    const float* __restrict__ bias, ushort* __restrict__ out)
{
    __shared__ float xs[2916];     // [3][3][18][18] padded neighborhood
    __shared__ float wsh[3240];    // [40][81]
    const int tid = threadIdx.x;
    const int bx = blockIdx.x;
    const int d2 = bx & 15, d1 = (bx >> 4) & 15, b = bx >> 8;
    const float* xb = x + (size_t)b * 65536;

    for (int i = tid; i < 2916; i += 256){
        int i4 = i % 18; int r1 = i / 18; int i3 = r1 % 18;
        int r2 = r1 / 18; int a2 = r2 % 3; int a1 = r2 / 3;
        int e1 = d1 + a1 - 1, e2 = d2 + a2 - 1, e3 = i3 - 1, e4 = i4 - 1;
        float v = 0.f;
        if ((unsigned)e1 < 16u && (unsigned)e2 < 16u && (unsigned)e3 < 16u && (unsigned)e4 < 16u)
            v = xb[((e1 * 16 + e2) * 16 + e3) * 16 + e4];
        xs[i] = v;
    }
    for (int i = tid; i < 3240; i += 256) wsh[i] = w[i];
    __syncthreads();

    const int d3 = tid >> 4, d4 = tid & 15;
    float acc[40];
    #pragma unroll
    for (int c = 0; c < 40; ++c) acc[c] = 0.f;

    for (int t1 = 0; t1 < 3; ++t1)
    for (int t2 = 0; t2 < 3; ++t2)
    for (int t3 = 0; t3 < 3; ++t3)
    #pragma unroll
    for (int t4 = 0; t4 < 3; ++t4){
        float xv = xs[((t1 * 3 + t2) * 18 + d3 + t3) * 18 + d4 + t4];
        int tap = ((t1 * 3 + t2) * 3 + t3) * 3 + t4;
        #pragma unroll
        for (int c = 0; c < 40; ++c) acc[c] += wsh[c * 81 + tap] * xv;
    }

    ushort* ob = out + ((size_t)bx * 256 + tid) * 64;
    #pragma unroll
    for (int c = 0; c < 40; ++c){
        float v = acc[c] + bias[c]; v = v > 0.f ? v : 0.f;
        ob[c] = f2bf(v);
    }
    #pragma unroll
    for (int c = 40; c < 64; ++c) ob[c] = 0;
}

// ---------------- Layer 6: 40 real (stored 48) -> Cout=1, direct fp32 -------------------
__global__ __launch_bounds__(256) void conv_l6(
    const ushort* __restrict__ in, const float* __restrict__ w,
    const float* __restrict__ bias, float* __restrict__ out)
{
    __shared__ float wsh[3240];    // [ci=40][81]
    const int tid = threadIdx.x;
    const int bx = blockIdx.x;
    const int d2 = bx & 15, d1 = (bx >> 4) & 15, b = bx >> 8;
    for (int i = tid; i < 3240; i += 256) wsh[i] = w[i];
    __syncthreads();

    const int d3 = tid >> 4, d4 = tid & 15;
    const ushort* inb = in + (size_t)b * 65536 * 48;
    float acc = 0.f;
    for (int t1 = 0; t1 < 3; ++t1){
        int e1 = d1 + t1 - 1; if ((unsigned)e1 >= 16u) continue;
        for (int t2 = 0; t2 < 3; ++t2){
            int e2 = d2 + t2 - 1; if ((unsigned)e2 >= 16u) continue;
            for (int t3 = 0; t3 < 3; ++t3){
                int e3 = d3 + t3 - 1; if ((unsigned)e3 >= 16u) continue;
                for (int t4 = 0; t4 < 3; ++t4){
                    int e4 = d4 + t4 - 1; if ((unsigned)e4 >= 16u) continue;
                    const ushort* p = inb + (size_t)(((e1 * 16 + e2) * 16 + e3) * 16 + e4) * 48;
                    int tap = ((t1 * 3 + t2) * 3 + t3) * 3 + t4;
                    #pragma unroll
                    for (int c8 = 0; c8 < 5; ++c8){
                        short8 v = *(const short8*)(p + c8 * 8);
                        #pragma unroll
                        for (int j = 0; j < 8; ++j)
                            acc += bf2f((ushort)v[j]) * wsh[(c8 * 8 + j) * 81 + tap];
                    }
                }
            }
        }
    }
    float v = acc + bias[0]; v = v > 0.f ? v : 0.f;
    out[(size_t)bx * 256 + tid] = v;
}

// ---------------- Weight repack: [co][ci][81] fp32 -> [81][ci/8][co][8] bf16 ------------
__global__ void repack_w(const float* __restrict__ w, ushort* __restrict__ wp,
                         int cin, int cout, int cin_s, int cout_c)
{
    const int total = 81 * cin_s * cout_c;
    for (int i = blockIdx.x * blockDim.x + threadIdx.x; i < total; i += gridDim.x * blockDim.x){
        int j = i & 7;
        int rest = i >> 3;
        int co = rest % cout_c;
        int rest2 = rest / cout_c;
        int ci_hi = rest2 % (cin_s >> 3);
        int t = rest2 / (cin_s >> 3);
        int ci = ci_hi * 8 + j;
        float v = (ci < cin && co < cout) ? w[((size_t)co * cin + ci) * 81 + t] : 0.f;
        wp[i] = f2bf(v);
    }
}

// ---------------- 16x16x32 MFMA implicit-GEMM conv layer --------------------------------
// in : [b][d1][d2][d3][d4][CIN_S]  bf16
// wp : [81][ci/8][COUT_TOT][8]     bf16 (B-fragment native)
// out: [b][d1][d2][d3][d4][OST]    bf16; cols [CREAL,OST) zero-filled explicitly (PADC>0)
// Block: 512 thr = 8 M-stacked waves; wave tile M32 x N=COUT_W (m2 x NT of 16x16x32).
// N split across grid strips when COUT_TOT > COUT_W. A chunk [256 pos][32ch] dbuf,
// reg-prefetched; B 3-tap chunk [12][COUT_W] dbuf, reg prefetch distance 2 steps.
template<int CIN_S, int COUT_W, int COUT_TOT, int OST, int CREAL, int PADC>
__global__ __launch_bounds__(512, 4) void conv16(
    const ushort* __restrict__ in, const ushort* __restrict__ wp,
    const float* __restrict__ bias, ushort* __restrict__ out)
{
    constexpr int KC   = CIN_S / 32;           // A chunks per plane
    constexpr int NT   = COUT_W / 16;          // n-frags per wave
    constexpr int APAD = 40;                   // A row stride (odd 16B-slot count)
    constexpr int A8   = 1024;                 // 16B units per A chunk
    constexpr int NLA  = A8 / 512;             // = 2
    constexpr int B8   = 12 * COUT_W;          // 16B units per 3-tap B chunk
    constexpr int NLB  = (B8 + 511) / 512;     // = 2

    __shared__ __attribute__((aligned(16))) ushort As[2][256 * APAD];
    __shared__ __attribute__((aligned(16))) ushort Bs[2][B8 * 8];

    const int tid  = threadIdx.x;
    const int lane = tid & 63;
    const int wm   = tid >> 6;                 // 0..7 (32-row M slice)
    const int r    = lane & 15;                // A-row offset / B-col / D-col
    const int g    = lane >> 4;                // k-group / D row-group

    // grid: [strips][512 plane blocks]; XCD-aware chunked swizzle on plane index
    const int p0 = blockIdx.x;
    const int strip = p0 >> 9;
    const int pp = p0 & 511;
    const int bx = (pp & 7) * 64 + (pp >> 3);
    const int d2 = bx & 15, d1 = (bx >> 4) & 15, b = bx >> 8;
    const int co_base = strip * COUT_W;

    const ushort* inb = in + (size_t)b * 65536 * CIN_S;

    // valid (t1,t2) groups packed 4 bits each
    unsigned long long gpack = 0ull; int ng = 0;
    #pragma unroll
    for (int gg = 0; gg < 9; ++gg){
        const int t1 = gg / 3, t2 = gg - (gg / 3) * 3;
        if ((unsigned)(d1 + t1 - 1) < 16u && (unsigned)(d2 + t2 - 1) < 16u){
            gpack |= ((unsigned long long)gg) << (ng * 4);
            ++ng;
        }
    }
    const int nchunk = ng * KC;
    const int nstep  = nchunk * 3;

    f32x4 acc[2][NT];
    #pragma unroll
    for (int mi = 0; mi < 2; ++mi)
        #pragma unroll
        for (int n = 0; n < NT; ++n)
            acc[mi][n] = (f32x4){0.f, 0.f, 0.f, 0.f};

    short8 areg[NLA];
    short8 brg0[NLB], brg1[NLB];

    auto loadAreg = [&](int c){
        const int gi = c / KC, kh = c - gi * KC;
        const int gg = (int)((gpack >> (gi * 4)) & 15ull);
        const int t1 = gg / 3, t2 = gg - t1 * 3;
        const ushort* src = inb + ((size_t)((d1 + t1 - 1) * 16 + (d2 + t2 - 1)) * 256) * CIN_S + kh * 32;
        #pragma unroll
        for (int k = 0; k < NLA; ++k){
            const int i = tid + k * 512;
            areg[k] = *(const short8*)(src + (size_t)(i >> 2) * CIN_S + (i & 3) * 8);
        }
    };
    auto writeA = [&](ushort* dst){
        #pragma unroll
        for (int k = 0; k < NLA; ++k){
            const int i = tid + k * 512;
            *(short8*)(dst + (i >> 2) * APAD + (i & 3) * 8) = areg[k];
        }
    };
    auto loadBreg = [&](int s, short8 (&brg)[NLB]){
        const int c = s / 3, t3 = s - c * 3;
        const int gi = c / KC, kh = c - gi * KC;
        const int gg = (int)((gpack >> (gi * 4)) & 15ull);
        const int tap0 = gg * 9 + t3 * 3;          // t4 = 0
        #pragma unroll
        for (int k = 0; k < NLB; ++k){
            const int i = tid + k * 512;
            if (i < B8){
                const int t4 = i / (4 * COUT_W);
                const int rest = i - t4 * (4 * COUT_W);
                const int gk = rest / COUT_W;
                const int col = rest - gk * COUT_W;
                brg[k] = *((const short8*)wp +
                           ((size_t)(tap0 + t4) * (CIN_S / 8) + kh * 4 + gk) * COUT_TOT + co_base + col);
            }
        }
    };
    auto writeB = [&](ushort* dst, short8 (&brg)[NLB]){
        #pragma unroll
        for (int k = 0; k < NLB; ++k){
            const int i = tid + k * 512;
            if (i < B8) *(short8*)(dst + i * 8) = brg[k];
        }
    };

    // prologue
    loadAreg(0);
    loadBreg(0, brg0);
    writeA(As[0]);
    writeB(Bs[0], brg0);
    if (nchunk > 1) loadAreg(1);
    if (nstep > 1) loadBreg(1, brg1);
    __syncthreads();

    int c = 0, t3 = 0;
    for (int s = 0; s < nstep; ++s){
        // ds-write next B chunk (regs loaded 2 steps ago)
        if (s + 1 < nstep){
            if ((s + 1) & 1) writeB(Bs[1], brg1); else writeB(Bs[0], brg0);
        }
        // ds-write next A chunk; refill areg 2 chunks ahead
        if (t3 == 0 && c + 1 < nchunk) writeA(As[(c + 1) & 1]);
        if (t3 == 1 && c + 2 < nchunk) loadAreg(c + 2);
        // issue global loads for B two steps ahead
        if (s + 2 < nstep){
            if (s & 1) loadBreg(s + 2, brg1); else loadBreg(s + 2, brg0);
        }

        // compute: 3 t4-taps x (m2 x NT) MFMA, K=32 per step
        const ushort* Ab = As[c & 1];
        const ushort* Bb = Bs[s & 1];
        __builtin_amdgcn_s_setprio(1);
        #pragma unroll
        for (int t4 = 0; t4 < 3; ++t4){
            const int e4 = r + t4 - 1;
            const bool v4 = (unsigned)e4 < 16u;
            short8 bfr[NT];
            #pragma unroll
            for (int n = 0; n < NT; ++n)
                bfr[n] = *(const short8*)(Bb + ((t4 * 4 + g) * COUT_W + n * 16 + r) * 8);
            #pragma unroll
            for (int mi = 0; mi < 2; ++mi){
                const int e3 = 2 * wm + mi + t3 - 1;
                short8 af = {0, 0, 0, 0, 0, 0, 0, 0};
                if (v4 && (unsigned)e3 < 16u)
                    af = *(const short8*)(Ab + (e3 * 16 + e4) * APAD + g * 8);
                #pragma unroll
                for (int n = 0; n < NT; ++n)
                    acc[mi][n] = __builtin_amdgcn_mfma_f32_16x16x32_bf16(af, bfr[n], acc[mi][n], 0, 0, 0);
            }
        }
        __builtin_amdgcn_s_setprio(0);

        __syncthreads();
        ++t3; if (t3 == 3){ t3 = 0; ++c; }
    }

    // epilogue: bias + ReLU + bf16 store. D frag: col = lane&15, row = g*4 + reg
    float bv[NT];
    #pragma unroll
    for (int n = 0; n < NT; ++n){
        const int co = co_base + n * 16 + r;
        bv[n] = (co < CREAL) ? bias[co] : 0.f;
    }
    ushort* ob = out + (size_t)bx * 256 * OST;
    #pragma unroll
    for (int mi = 0; mi < 2; ++mi){
        #pragma unroll
        for (int n = 0; n < NT; ++n){
            const int co = co_base + n * 16 + r;
            #pragma unroll
            for (int j = 0; j < 4; ++j){
                const int row = 32 * wm + 16 * mi + g * 4 + j;
                float v = acc[mi][n][j] + bv[n];
                v = v > 0.f ? v : 0.f;
                ob[(size_t)row * OST + co] = f2bf(v);
            }
        }
    }
    if (PADC > 0 && lane < 32){
        const int row = 32 * wm + lane;
        const short8 z = {0, 0, 0, 0, 0, 0, 0, 0};
        #pragma unroll
        for (int pc = 0; pc < PADC; pc += 8)
            *(short8*)(ob + (size_t)row * OST + CREAL + pc) = z;
    }
}

extern "C" void kernel_launch(void* const* d_in, const int* in_sizes, int n_in,
                              void* d_out, int out_size, void* d_ws, size_t ws_size,
                              hipStream_t stream) {
    const float* x  = (const float*)d_in[0];
    const float* w1 = (const float*)d_in[1];  const float* b1 = (const float*)d_in[2];
    const float* w2 = (const float*)d_in[3];  const float* b2 = (const float*)d_in[4];
    const float* w3 = (const float*)d_in[5];  const float* b3 = (const float*)d_in[6];
    const float* w4 = (const float*)d_in[7];  const float* b4 = (const float*)d_in[8];
    const float* w5 = (const float*)d_in[9];  const float* b5 = (const float*)d_in[10];
    const float* w6 = (const float*)d_in[11]; const float* b6 = (const float*)d_in[12];

    // workspace layout (bf16 ushorts):
    ushort* bufA = (ushort*)d_ws;                       // [131072][160] : 41.9 MB
    ushort* bufB = bufA + (size_t)131072 * 160;         // [131072][96]  : 25.2 MB
    ushort* wp2  = bufB + (size_t)131072 * 96;          // 81*8*80*8
    ushort* wp3  = wp2 + (size_t)81 * 64 * 80;          // 81*12*160*8
    ushort* wp4  = wp3 + (size_t)81 * 96 * 160;         // 81*20*80*8
    ushort* wp5  = wp4 + (size_t)81 * 160 * 80;         // 81*12*48*8

    repack_w<<<512, 256, 0, stream>>>(w2, wp2, 40, 80, 64, 80);
    repack_w<<<512, 256, 0, stream>>>(w3, wp3, 80, 160, 96, 160);
    repack_w<<<512, 256, 0, stream>>>(w4, wp4, 160, 80, 160, 80);
    repack_w<<<512, 256, 0, stream>>>(w5, wp5, 80, 40, 96, 48);

    conv_l1<<<512, 256, 0, stream>>>(x, w1, b1, bufA);
    //       CIN_S  W   TOT  OST  CREAL PADC
    conv16<  64,   80,  80,  96,  80,  16><<< 512, 512, 0, stream>>>(bufA, wp2, b2, bufB);
    conv16<  96,   80, 160, 160, 160,   0><<<1024, 512, 0, stream>>>(bufB, wp3, b3, bufA);
    conv16< 160,   80,  80,  96,  80,  16><<< 512, 512, 0, stream>>>(bufA, wp4, b4, bufB);
    conv16<  96,   48,  48,  48,  40,   0><<< 512, 512, 0, stream>>>(bufB, wp5, b5, bufA);
    conv_l6<<<512, 256, 0, stream>>>(bufA, w6, b6, (float*)d_out);
}